// Round 3
// baseline (1096.117 us; speedup 1.0000x reference)
//
#include <hip/hip_runtime.h>
#include <hip/hip_bf16.h>
#include <stdint.h>

// Problem constants
#define M_ROWS   32768            // 4*8192
#define K_DIM    1024             // D_MODEL
#define N_COLS   4112             // TOTAL
#define N_PAD    4224             // 33*128 (W padded with zero rows)
#define SEC_ELEMS 33554432ull     // 32768*1024, one output section

#define XN4 8388608               // x float4 count (32768*1024/4)
#define WN4 1081344               // padded W float4 count (4224*1024/4)
#define WV4 1052672               // valid W float4 count (4112*1024/4)

typedef __bf16  bf16x8 __attribute__((ext_vector_type(8)));
typedef float   f32x4  __attribute__((ext_vector_type(4)));

__device__ __forceinline__ unsigned short f2bf(float f) {
    // round-to-nearest-even fp32 -> bf16
    uint32_t u = __float_as_uint(f);
    u += 0x7fffu + ((u >> 16) & 1u);
    return (unsigned short)(u >> 16);
}

// ---- fused conversion kernel (x and W in one grid-stride pass) ----------
__global__ __launch_bounds__(256) void cvt_kernel(
        const float* __restrict__ x, const float* __restrict__ W,
        unsigned short* __restrict__ xb, unsigned short* __restrict__ Wb) {
    const int stride = gridDim.x * 256;
    for (int i = blockIdx.x * 256 + threadIdx.x; i < XN4 + WN4; i += stride) {
        if (i < XN4) {
            float4 v = ((const float4*)x)[i];
            ushort4 o;
            o.x = f2bf(v.x); o.y = f2bf(v.y); o.z = f2bf(v.z); o.w = f2bf(v.w);
            ((ushort4*)xb)[i] = o;
        } else {
            const int j = i - XN4;
            ushort4 o;
            o.x = 0; o.y = 0; o.z = 0; o.w = 0;
            if (j < WV4) {
                float4 v = ((const float4*)W)[j];
                o.x = f2bf(v.x); o.y = f2bf(v.y); o.z = f2bf(v.z); o.w = f2bf(v.w);
            }
            ((ushort4*)Wb)[j] = o;
        }
    }
}

// ---- main GEMM: 128x128 tile, double-buffered LDS, T3-min 2-phase -------
// Prefetch STAGE(kt+1) issued BEFORE COMPUTE(kt); one __syncthreads() per
// K-step (compiler emits the vmcnt(0)+s_barrier drain -> race-free; each
// wave's loads are drained before any wave passes the barrier).
#define GLOAD_LDS16(gp, lp)                                                  \
    __builtin_amdgcn_global_load_lds(                                        \
        (const __attribute__((address_space(1))) void*)(gp),                 \
        (__attribute__((address_space(3))) void*)(lp), 16, 0, 0)

__global__ __launch_bounds__(256) void gemm_kernel(
        const unsigned short* __restrict__ A,   // M_ROWS x 1024 bf16
        const unsigned short* __restrict__ B,   // N_PAD  x 1024 bf16 (row = out col)
        float* __restrict__ out) {
    __shared__ unsigned short sA[2][128 * 32];
    __shared__ unsigned short sB[2][128 * 32];

    const int t  = threadIdx.x;
    const int w  = t >> 6;       // wave 0..3
    const int l  = t & 63;       // lane

    // XCD-bijective swizzle: nwg = 8448 = 8*1056. HW round-robins consecutive
    // blockIdx across the 8 XCDs; remap so each XCD gets a contiguous chunk
    // of the (by-major, bx-fastest) work list -> each A row panel is fetched
    // into exactly one XCD's L2 and reused by its 33 column tiles.
    const int bid = blockIdx.x;
    const int nid = (bid & 7) * 1056 + (bid >> 3);
    const int by  = nid / 33;          // row tile 0..255
    const int bx  = nid - by * 33;     // col tile 0..32

    // staging: each wave fills two 16-row segments of each tile (16B/lane)
    const int s0 = 2 * w, s1 = 2 * w + 1;
    const int lr = l >> 2;            // row within segment
    const int lk = (l & 3) * 8;       // k offset (8 bf16 = 16B)
    const unsigned short* a0 = A + (size_t)(by * 128 + s0 * 16 + lr) * K_DIM + lk;
    const unsigned short* a1 = A + (size_t)(by * 128 + s1 * 16 + lr) * K_DIM + lk;
    const unsigned short* b0 = B + (size_t)(bx * 128 + s0 * 16 + lr) * K_DIM + lk;
    const unsigned short* b1 = B + (size_t)(bx * 128 + s1 * 16 + lr) * K_DIM + lk;

    const int wm   = (w >> 1) * 64;   // wave's 64x64 quadrant
    const int wn   = (w & 1) * 64;
    const int quad = l >> 4;
    const int l16  = l & 15;

    f32x4 acc[4][4] = {};

#define STAGE(kt, c) do {                                                    \
        const size_t o_ = (size_t)(kt) * 32;                                 \
        GLOAD_LDS16(a0 + o_, &sA[c][s0 * 512]);                              \
        GLOAD_LDS16(a1 + o_, &sA[c][s1 * 512]);                              \
        GLOAD_LDS16(b0 + o_, &sB[c][s0 * 512]);                              \
        GLOAD_LDS16(b1 + o_, &sB[c][s1 * 512]);                              \
    } while (0)

#define COMPUTE(c) do {                                                      \
        bf16x8 af[4], bfr[4];                                                \
        _Pragma("unroll")                                                    \
        for (int i_ = 0; i_ < 4; ++i_)                                       \
            af[i_] = *(const bf16x8*)&sA[c][(wm + i_ * 16 + l16) * 32 + quad * 8]; \
        _Pragma("unroll")                                                    \
        for (int j_ = 0; j_ < 4; ++j_)                                       \
            bfr[j_] = *(const bf16x8*)&sB[c][(wn + j_ * 16 + l16) * 32 + quad * 8]; \
        _Pragma("unroll")                                                    \
        for (int i_ = 0; i_ < 4; ++i_)                                       \
            _Pragma("unroll")                                                \
            for (int j_ = 0; j_ < 4; ++j_)                                   \
                acc[i_][j_] = __builtin_amdgcn_mfma_f32_16x16x32_bf16(       \
                    af[i_], bfr[j_], acc[i_][j_], 0, 0, 0);                  \
    } while (0)

    STAGE(0, 0);
    __syncthreads();                       // tile 0 resident
    for (int kt = 0; kt < 30; kt += 2) {
        STAGE(kt + 1, 1);                  // prefetch next tile (in flight)
        COMPUTE(0);                        // compute current under the loads
        __syncthreads();                   // drain prefetch + guard buf reuse
        STAGE(kt + 2, 0);
        COMPUTE(1);
        __syncthreads();
    }
    STAGE(31, 1);
    COMPUTE(0);                            // tile 30
    __syncthreads();                       // tile 31 resident
    COMPUTE(1);                            // tile 31

#undef STAGE
#undef COMPUTE

    // Epilogue. C/D layout: col = lane&15, row = quad*4 + reg (m89/m91 verified).
    const int row0 = by * 128 + wm + quad * 4;
    if (bx < 32) {
        const int  sec = bx >> 3;                       // 0:Q 1:K 2:V 3:gate
        const int  cb  = ((bx & 7) << 7) + wn + l16;    // col within 1024-wide section
        const bool isG = (sec == 3);
        float* o = out + (size_t)sec * SEC_ELEMS;
        #pragma unroll
        for (int i = 0; i < 4; ++i) {
            #pragma unroll
            for (int r = 0; r < 4; ++r) {
                const int row = row0 + i * 16 + r;
                const size_t base = (size_t)row * 1024 + cb;
                #pragma unroll
                for (int j = 0; j < 4; ++j) {
                    float v = acc[i][j][r];
                    if (isG) v = v / (1.f + __expf(-v));   // silu
                    o[base + j * 16] = v;
                }
            }
        }
    } else {
        // alpha tile: only cols 4096..4111 valid (wn==0, j==0, l16 0..15)
        if (wn == 0) {
            float* o = out + 4 * SEC_ELEMS;
            #pragma unroll
            for (int i = 0; i < 4; ++i) {
                #pragma unroll
                for (int r = 0; r < 4; ++r) {
                    const int row = row0 + i * 16 + r;
                    const float v = acc[i][0][r];
                    o[(size_t)row * 16 + l16] = 1.f / (1.f + __expf(-v));  // sigmoid
                }
            }
        }
    }
}

// ---- K row-normalization: one wave per row (4 float4/lane), no LDS ------
__global__ __launch_bounds__(256) void knorm_kernel(float* __restrict__ out) {
    const int nwaves = (gridDim.x * 256) >> 6;
    const int gw = (blockIdx.x * 256 + threadIdx.x) >> 6;
    const int l  = threadIdx.x & 63;
    for (int m = gw; m < M_ROWS; m += nwaves) {
        float4* k = (float4*)(out + SEC_ELEMS + (size_t)m * 1024);
        // row = 1024 floats = 256 float4; 64 lanes x 4 float4 each
        float4 v0 = k[l];
        float4 v1 = k[l + 64];
        float4 v2 = k[l + 128];
        float4 v3 = k[l + 192];
        float ss = v0.x*v0.x + v0.y*v0.y + v0.z*v0.z + v0.w*v0.w
                 + v1.x*v1.x + v1.y*v1.y + v1.z*v1.z + v1.w*v1.w
                 + v2.x*v2.x + v2.y*v2.y + v2.z*v2.z + v2.w*v2.w
                 + v3.x*v3.x + v3.y*v3.y + v3.z*v3.z + v3.w*v3.w;
        #pragma unroll
        for (int off = 1; off < 64; off <<= 1)
            ss += __shfl_xor(ss, off);                 // all 64 lanes get total
        const float sc = 1.f / fmaxf(sqrtf(ss), 1e-12f);
        v0.x *= sc; v0.y *= sc; v0.z *= sc; v0.w *= sc;
        v1.x *= sc; v1.y *= sc; v1.z *= sc; v1.w *= sc;
        v2.x *= sc; v2.y *= sc; v2.z *= sc; v2.w *= sc;
        v3.x *= sc; v3.y *= sc; v3.z *= sc; v3.w *= sc;
        k[l]       = v0;
        k[l + 64]  = v1;
        k[l + 128] = v2;
        k[l + 192] = v3;
    }
}

// ---- launch -------------------------------------------------------------
extern "C" void kernel_launch(void* const* d_in, const int* in_sizes, int n_in,
                              void* d_out, int out_size, void* d_ws, size_t ws_size,
                              hipStream_t stream) {
    const float* x = (const float*)d_in[0];   // (4,8192,1024) fp32
    const float* W = (const float*)d_in[1];   // (4112,1024)  fp32
    float* out = (float*)d_out;

    unsigned short* xb = (unsigned short*)d_ws;                 // 32768x1024 bf16 (64 MiB)
    unsigned short* Wb = xb + (size_t)M_ROWS * K_DIM;           // 4224x1024 bf16  (8.25 MiB)

    cvt_kernel<<<2048, 256, 0, stream>>>(x, W, xb, Wb);
    gemm_kernel<<<8448, 256, 0, stream>>>(xb, Wb, out);
    knorm_kernel<<<2048, 256, 0, stream>>>(out);
}